// Round 6
// baseline (67.277 us; speedup 1.0000x reference)
//
#include <hip/hip_runtime.h>

#define NBLOCKS 2048
#define NTHREADS 512
#define FIXED_SCALE 1048576.0f   // 2^20

typedef float __attribute__((ext_vector_type(4))) fx4;
typedef int   __attribute__((ext_vector_type(4))) ix4;

__device__ __forceinline__ float wave_reduce_sum(float v) {
    #pragma unroll
    for (int off = 32; off > 0; off >>= 1)
        v += __shfl_down(v, off, 64);
    return v;
}

__device__ __forceinline__ float sample_loss(float p0, float p1, float p2, int lab) {
    // per_sample = lse - (eps/C)*(p0+p1+p2) - (1-eps)*p_lab ; return w[lab]*per_sample
    float m = fmaxf(p0, fmaxf(p1, p2));
    float e = __expf(p0 - m) + __expf(p1 - m) + __expf(p2 - m);
    float lse = m + __logf(e);
    float pl = (lab == 0) ? p0 : ((lab == 1) ? p1 : p2);
    float w  = (lab == 0) ? 10.0f : ((lab == 1) ? (10.0f / 3.0f) : (10.0f / 6.0f));
    float per = lse - (0.1f / 3.0f) * (p0 + p1 + p2) - 0.9f * pl;
    return w * per;
}

__global__ void __launch_bounds__(NTHREADS)
ce_onepass_kernel(const float* __restrict__ pred,
                  const int* __restrict__ label,
                  unsigned long long* __restrict__ total,
                  unsigned long long* __restrict__ count,
                  float* __restrict__ out, int n, float inv_n) {
    int tid = blockIdx.x * blockDim.x + threadIdx.x;
    int nthreads = gridDim.x * blockDim.x;   // 1048576 threads
    int groups = n >> 3;                      // 8 samples per group -> exactly 1 iter
    float acc = 0.0f;

    for (int g = tid; g < groups; g += nthreads) {
        const fx4* p4 = reinterpret_cast<const fx4*>(pred + (size_t)g * 24);
        const ix4* l4 = reinterpret_cast<const ix4*>(label) + (size_t)g * 2;
        fx4 a = p4[0];
        fx4 b = p4[1];
        fx4 c = p4[2];
        fx4 d = p4[3];
        fx4 e = p4[4];
        fx4 f = p4[5];
        ix4 l0 = l4[0];
        ix4 l1 = l4[1];
        acc += sample_loss(a.x, a.y, a.z, l0.x);
        acc += sample_loss(a.w, b.x, b.y, l0.y);
        acc += sample_loss(b.z, b.w, c.x, l0.z);
        acc += sample_loss(c.y, c.z, c.w, l0.w);
        acc += sample_loss(d.x, d.y, d.z, l1.x);
        acc += sample_loss(d.w, e.x, e.y, l1.y);
        acc += sample_loss(e.z, e.w, f.x, l1.z);
        acc += sample_loss(f.y, f.z, f.w, l1.w);
    }
    // tail (n % 8 != 0): global thread 0 only (N=8388608 -> no-op)
    if (tid == 0) {
        for (int i = groups << 3; i < n; ++i) {
            acc += sample_loss(pred[(size_t)i * 3], pred[(size_t)i * 3 + 1],
                               pred[(size_t)i * 3 + 2], label[i]);
        }
    }

    __shared__ float sdata[NTHREADS / 64];
    float wsum = wave_reduce_sum(acc);
    int lane = threadIdx.x & 63;
    int wid  = threadIdx.x >> 6;
    if (lane == 0) sdata[wid] = wsum;
    __syncthreads();
    if (threadIdx.x == 0) {
        float s = 0.0f;
        #pragma unroll
        for (int i = 0; i < NTHREADS / 64; ++i) s += sdata[i];
        // Fixed-point relaxed atomic: integer add is order-independent ->
        // bit-deterministic total, and RELAXED emits no L2 writeback/invalidate
        // (the cache-maintenance storm that sank the R3/R4 fused version).
        long long fx = llrintf(s * FIXED_SCALE);
        unsigned long long oldt =
            __hip_atomic_fetch_add(total, (unsigned long long)fx,
                                   __ATOMIC_RELAXED, __HIP_MEMORY_SCOPE_AGENT);
        // Data dependency (bump == 1 always) orders count-add after total-add
        // without a fence: count RMW issues only after total RMW's response.
        unsigned long long bump = 1ull + (oldt >> 63);
        unsigned long long oldc =
            __hip_atomic_fetch_add(count, bump,
                                   __ATOMIC_RELAXED, __HIP_MEMORY_SCOPE_AGENT);
        if (oldc == (unsigned long long)(gridDim.x - 1)) {
            // All 2048 total-adds have completed at the LLC. Read via RMW
            // (coherent point, bypasses any stale L1 copy).
            unsigned long long tot =
                __hip_atomic_fetch_add(total, 0ull,
                                       __ATOMIC_RELAXED, __HIP_MEMORY_SCOPE_AGENT);
            out[0] = (float)(long long)tot * (inv_n / FIXED_SCALE);
        }
    }
}

extern "C" void kernel_launch(void* const* d_in, const int* in_sizes, int n_in,
                              void* d_out, int out_size, void* d_ws, size_t ws_size,
                              hipStream_t stream) {
    const float* pred = (const float*)d_in[0];
    const int* label = (const int*)d_in[1];
    int n = in_sizes[1];  // number of samples (pred is n*3)
    unsigned long long* total = (unsigned long long*)d_ws;
    unsigned long long* count = total + 1;
    float* out = (float*)d_out;

    // ws is poisoned (0xAA) once and never re-poisoned between replays, and we
    // leave total/count dirty after each call: reset both every call.
    (void)hipMemsetAsync(d_ws, 0, 2 * sizeof(unsigned long long), stream);
    ce_onepass_kernel<<<NBLOCKS, NTHREADS, 0, stream>>>(pred, label, total, count,
                                                        out, n, 1.0f / (float)n);
}

// Round 7
// 28.114 us; speedup vs baseline: 2.3930x; 2.3930x over previous
//
#include <hip/hip_runtime.h>

#define NBLOCKS 2048
#define NTHREADS 256
#define TILE 1024               // samples per block-tile: 12 KB pred + 4 KB label LDS

typedef float __attribute__((ext_vector_type(4))) fx4;
typedef int   __attribute__((ext_vector_type(4))) ix4;

__device__ __forceinline__ float wave_reduce_sum(float v) {
    #pragma unroll
    for (int off = 32; off > 0; off >>= 1)
        v += __shfl_down(v, off, 64);
    return v;
}

__device__ __forceinline__ float sample_loss(float p0, float p1, float p2, int lab) {
    // per_sample = lse - (eps/C)*(p0+p1+p2) - (1-eps)*p_lab ; return w[lab]*per_sample
    float m = fmaxf(p0, fmaxf(p1, p2));
    float e = __expf(p0 - m) + __expf(p1 - m) + __expf(p2 - m);
    float lse = m + __logf(e);
    float pl = (lab == 0) ? p0 : ((lab == 1) ? p1 : p2);
    float w  = (lab == 0) ? 10.0f : ((lab == 1) ? (10.0f / 3.0f) : (10.0f / 6.0f));
    float per = lse - (0.1f / 3.0f) * (p0 + p1 + p2) - 0.9f * pl;
    return w * per;
}

__global__ void __launch_bounds__(NTHREADS, 8)
ce_partial_kernel(const float* __restrict__ pred,
                  const int* __restrict__ label,
                  float* __restrict__ partials, int n) {
    // Lane-contiguous (fully coalesced) global loads + LDS transpose.
    __shared__ float sp[3 * TILE];   // 12 KB, sample s at sp[3s..3s+2]
    __shared__ int   sl[TILE];       // 4 KB
    __shared__ float sdata[NTHREADS / 64];

    const int t = threadIdx.x;
    const int ntiles = n >> 10;      // full 1024-sample tiles
    float acc = 0.0f;

    fx4 r0, r1, r2; ix4 rl;
    int tile = blockIdx.x;
    if (tile < ntiles) {
        const fx4* p4 = reinterpret_cast<const fx4*>(pred + (size_t)tile * (3 * TILE));
        r0 = p4[t];
        r1 = p4[t + 256];
        r2 = p4[t + 512];
        rl = reinterpret_cast<const ix4*>(label + (size_t)tile * TILE)[t];
    }
    while (tile < ntiles) {
        int next = tile + gridDim.x;
        // stage current tile (contiguous b128 writes: conflict-free)
        reinterpret_cast<fx4*>(sp)[t]       = r0;
        reinterpret_cast<fx4*>(sp)[t + 256] = r1;
        reinterpret_cast<fx4*>(sp)[t + 512] = r2;
        reinterpret_cast<ix4*>(sl)[t]       = rl;
        __syncthreads();
        if (next < ntiles) {  // issue next tile's loads; they fly under compute
            const fx4* p4 = reinterpret_cast<const fx4*>(pred + (size_t)next * (3 * TILE));
            r0 = p4[t];
            r1 = p4[t + 256];
            r2 = p4[t + 512];
            rl = reinterpret_cast<const ix4*>(label + (size_t)next * TILE)[t];
        }
        // strided sample assignment: banks (3t+j)%32, gcd(3,32)=1 -> 2-way (free)
        #pragma unroll
        for (int k = 0; k < 4; ++k) {
            int s = t + (k << 8);
            acc += sample_loss(sp[3 * s], sp[3 * s + 1], sp[3 * s + 2], sl[s]);
        }
        __syncthreads();
        tile = next;
    }
    // tail samples (n % 1024): serial on one thread (no-op for N = 2^23)
    if (blockIdx.x == 0 && t == 0) {
        for (int i = ntiles << 10; i < n; ++i) {
            acc += sample_loss(pred[(size_t)i * 3], pred[(size_t)i * 3 + 1],
                               pred[(size_t)i * 3 + 2], label[i]);
        }
    }

    float wsum = wave_reduce_sum(acc);
    int lane = t & 63;
    int wid  = t >> 6;
    if (lane == 0) sdata[wid] = wsum;
    __syncthreads();
    if (t == 0) {
        float s = 0.0f;
        #pragma unroll
        for (int i = 0; i < NTHREADS / 64; ++i) s += sdata[i];
        partials[blockIdx.x] = s;
    }
}

__global__ void __launch_bounds__(64)
ce_final_kernel(const float* __restrict__ partials, float* __restrict__ out,
                float inv_n) {
    // single wave: 2048 partials = 64 lanes x 8 float4
    int l = threadIdx.x;
    fx4 s4 = {0.0f, 0.0f, 0.0f, 0.0f};
    #pragma unroll
    for (int k = 0; k < 8; ++k)
        s4 += reinterpret_cast<const fx4*>(partials)[l + (k << 6)];
    float v = s4.x + s4.y + s4.z + s4.w;
    v = wave_reduce_sum(v);
    if (l == 0) out[0] = v * inv_n;
}

extern "C" void kernel_launch(void* const* d_in, const int* in_sizes, int n_in,
                              void* d_out, int out_size, void* d_ws, size_t ws_size,
                              hipStream_t stream) {
    const float* pred = (const float*)d_in[0];
    const int* label = (const int*)d_in[1];
    int n = in_sizes[1];  // number of samples (pred is n*3)
    float* partials = (float*)d_ws;
    float* out = (float*)d_out;

    ce_partial_kernel<<<NBLOCKS, NTHREADS, 0, stream>>>(pred, label, partials, n);
    ce_final_kernel<<<1, 64, 0, stream>>>(partials, out, 1.0f / (float)n);
}